// Round 1
// baseline (161.686 us; speedup 1.0000x reference)
//
#include <hip/hip_runtime.h>

#define L_SEQ 32768
#define NDIM 256
#define HDIM 256
#define NCAT 512   // 2*NDIM (re/im interleaved)
#define LC 64      // scan chunk length
#define NCHUNK 512 // L_SEQ / LC

typedef unsigned short u16;
typedef unsigned int u32;
typedef __bf16 bf16x8 __attribute__((ext_vector_type(8)));
typedef float f32x4 __attribute__((ext_vector_type(4)));
typedef __attribute__((address_space(3))) void lds_void;
typedef const __attribute__((address_space(1))) void gbl_void;

__device__ __forceinline__ u16 f2bf(float f) {
  u32 u = __builtin_bit_cast(u32, f);
  u = u + 0x7fffu + ((u >> 16) & 1u);
  return (u16)(u >> 16);
}

// ---------------------------------------------------------------------------
// PREP: x -> bf16, build Bcat (512x256 bf16), Ccat (256x512 bf16), lambda tables
// ---------------------------------------------------------------------------
__global__ __launch_bounds__(256) void prep_kernel(
    const float* __restrict__ x,
    const float* __restrict__ nu_log, const float* __restrict__ theta_log,
    const float* __restrict__ B_re, const float* __restrict__ B_im,
    const float* __restrict__ C_re, const float* __restrict__ C_im,
    const float* __restrict__ gamma_log,
    u16* __restrict__ x_bf, u16* __restrict__ Bcat, u16* __restrict__ Ccat,
    float2* __restrict__ lam, float2* __restrict__ lam64)
{
  const int blk = blockIdx.x, tid = threadIdx.x;
  if (blk < 2048) {
    // x: 8,388,608 floats = 2048 blocks * 1024 float4
    const float4* src = ((const float4*)x) + (size_t)blk * 1024;
    ushort4* dst = ((ushort4*)x_bf) + (size_t)blk * 1024;
#pragma unroll
    for (int j = 0; j < 4; ++j) {
      float4 v = src[j * 256 + tid];
      dst[j * 256 + tid] = make_ushort4(f2bf(v.x), f2bf(v.y), f2bf(v.z), f2bf(v.w));
    }
  } else if (blk < 2560) {
    // Bcat row b2: even row = B_re * e^gamma, odd row = B_im * e^gamma
    int b2 = blk - 2048;
    int jj = b2 >> 1, p = b2 & 1;
    float g = expf(gamma_log[jj]);
    const float* src = (p ? B_im : B_re) + (size_t)jj * HDIM;
    Bcat[(size_t)b2 * HDIM + tid] = f2bf(src[tid] * g);
  } else if (blk < 2816) {
    // Ccat row h: col 2j = C_re[h][j], col 2j+1 = -C_im[h][j]
    int h = blk - 2560;
#pragma unroll
    for (int half = 0; half < 2; ++half) {
      int nc = half * 256 + tid;
      int jj = nc >> 1, p = nc & 1;
      float v = p ? -C_im[(size_t)h * NDIM + jj] : C_re[(size_t)h * NDIM + jj];
      Ccat[(size_t)h * NCAT + nc] = f2bf(v);
    }
  } else {
    // lambda and lambda^LC tables
    float nu_e = expf(nu_log[tid]);
    float th = expf(theta_log[tid]);
    float r = expf(-nu_e);
    lam[tid] = make_float2(r * cosf(th), r * sinf(th));
    float r64 = expf(-(float)LC * nu_e);
    float ph = (float)LC * th;
    lam64[tid] = make_float2(r64 * cosf(ph), r64 * sinf(ph));
  }
}

// ---------------------------------------------------------------------------
// GEMM (B^T layout): C[m][n] = sum_k A[m][k] * Bm[n][k]; optional +x*D epilogue
// 128x128 tile, BK=32, 4 waves, m97-style global_load_lds staging
// ---------------------------------------------------------------------------
template <bool EPI_XD>
__global__ __launch_bounds__(256) void gemm_bt_kernel(
    const u16* __restrict__ A,   // M x K bf16
    const u16* __restrict__ Bm,  // N x K bf16
    float* __restrict__ Cout,    // M x N f32
    int M, int N, int K,
    const float* __restrict__ xin, const float* __restrict__ Dv)
{
  constexpr int BM = 128, BN = 128, BK = 32;
  __shared__ u16 lA[BM * BK];
  __shared__ u16 lB[BN * BK];
  const int tid = threadIdx.x;
  const int lane = tid & 63, wave = tid >> 6;
  const int bn = blockIdx.x, bm = blockIdx.y;
  const int row0 = bm * BM, col0 = bn * BN;
  const int wm = (wave >> 1) * 64, wn = (wave & 1) * 64;
  const int fr = lane & 15, fo = (lane >> 4) * 8;

  f32x4 acc[4][4] = {};
  const int nkt = K / BK;
  for (int kt = 0; kt < nkt; ++kt) {
    const int k0 = kt * BK;
#pragma unroll
    for (int j = 0; j < 2; ++j) {
      int chunk = j * 256 + tid;          // 512 chunks of 16B per tile
      int r = chunk >> 2, c = chunk & 3;
      const u16* ga = A + (size_t)(row0 + r) * K + (k0 + c * 8);
      const u16* gb = Bm + (size_t)(col0 + r) * K + (k0 + c * 8);
      __builtin_amdgcn_global_load_lds((gbl_void*)ga, (lds_void*)&lA[chunk * 8], 16, 0, 0);
      __builtin_amdgcn_global_load_lds((gbl_void*)gb, (lds_void*)&lB[chunk * 8], 16, 0, 0);
    }
    __syncthreads();

    bf16x8 af[4], bfr[4];
#pragma unroll
    for (int i = 0; i < 4; ++i) {
      af[i]  = *reinterpret_cast<const bf16x8*>(&lA[(wm + i * 16 + fr) * BK + fo]);
      bfr[i] = *reinterpret_cast<const bf16x8*>(&lB[(wn + i * 16 + fr) * BK + fo]);
    }
#pragma unroll
    for (int i = 0; i < 4; ++i)
#pragma unroll
      for (int j = 0; j < 4; ++j)
        acc[i][j] = __builtin_amdgcn_mfma_f32_16x16x32_bf16(af[i], bfr[j], acc[i][j], 0, 0, 0);
    __syncthreads();
  }

  // C/D layout: col = lane&15, row = (lane>>4)*4 + reg
  const int fq = lane >> 4;
#pragma unroll
  for (int i = 0; i < 4; ++i)
#pragma unroll
    for (int j = 0; j < 4; ++j) {
      int cg = col0 + wn + j * 16 + fr;
#pragma unroll
      for (int r = 0; r < 4; ++r) {
        int rg = row0 + wm + i * 16 + fq * 4 + r;
        float v = acc[i][j][r];
        if (EPI_XD) v += xin[(size_t)rg * N + cg] * Dv[cg];
        Cout[(size_t)rg * N + cg] = v;
      }
    }
}

// ---------------------------------------------------------------------------
// Scan phase 1: per-chunk final state (read-only over Bu)
// ---------------------------------------------------------------------------
__global__ __launch_bounds__(256) void scan_carry_kernel(
    const float2* __restrict__ Bu2, const float2* __restrict__ lam,
    float2* __restrict__ carry)
{
  const int n = threadIdx.x, b = blockIdx.x;
  const float2 la = lam[n];
  float sre = 0.f, sim = 0.f;
  const float2* p = Bu2 + (size_t)b * LC * NDIM + n;
#pragma unroll 8
  for (int j = 0; j < LC; ++j) {
    float2 bu = p[(size_t)j * NDIM];
    float nre = la.x * sre - la.y * sim + bu.x;
    float nim = la.x * sim + la.y * sre + bu.y;
    sre = nre; sim = nim;
  }
  carry[(size_t)b * NDIM + n] = make_float2(sre, sim);
}

// ---------------------------------------------------------------------------
// Scan phase 2: cross-chunk scan with constant coefficient lambda^LC
// corr[b] = state entering chunk b (corr[0] = 0)
// ---------------------------------------------------------------------------
__global__ __launch_bounds__(256) void carry_scan_kernel(
    const float2* __restrict__ carry, const float2* __restrict__ lam64,
    float2* __restrict__ corr)
{
  const int n = threadIdx.x;
  const float2 a = lam64[n];
  float cre = 0.f, cim = 0.f;
  corr[n] = make_float2(0.f, 0.f);
#pragma unroll 4
  for (int b = 0; b < NCHUNK - 1; ++b) {
    float2 lastb = carry[(size_t)b * NDIM + n];
    float nre = a.x * cre - a.y * cim + lastb.x;
    float nim = a.x * cim + a.y * cre + lastb.y;
    cre = nre; cim = nim;
    corr[(size_t)(b + 1) * NDIM + n] = make_float2(cre, cim);
  }
}

// ---------------------------------------------------------------------------
// Scan phase 3: recompute chunk seeded with carry, emit bf16 states (L x 512)
// ---------------------------------------------------------------------------
__global__ __launch_bounds__(256) void scan_apply_kernel(
    const float2* __restrict__ Bu2, const float2* __restrict__ lam,
    const float2* __restrict__ corr, u16* __restrict__ Sbf)
{
  const int n = threadIdx.x, b = blockIdx.x;
  const float2 la = lam[n];
  const float2 c = corr[(size_t)b * NDIM + n];
  float sre = c.x, sim = c.y;
  const float2* p = Bu2 + (size_t)b * LC * NDIM + n;
  ushort2* q = ((ushort2*)Sbf) + (size_t)b * LC * NDIM + n;
#pragma unroll 4
  for (int j = 0; j < LC; ++j) {
    float2 bu = p[(size_t)j * NDIM];
    float nre = la.x * sre - la.y * sim + bu.x;
    float nim = la.x * sim + la.y * sre + bu.y;
    sre = nre; sim = nim;
    q[(size_t)j * NDIM] = make_ushort2(f2bf(sre), f2bf(sim));
  }
}

// ---------------------------------------------------------------------------
extern "C" void kernel_launch(void* const* d_in, const int* in_sizes, int n_in,
                              void* d_out, int out_size, void* d_ws, size_t ws_size,
                              hipStream_t stream)
{
  (void)in_sizes; (void)n_in; (void)out_size; (void)ws_size;
  const float* x         = (const float*)d_in[0];
  const float* nu_log    = (const float*)d_in[1];
  const float* theta_log = (const float*)d_in[2];
  const float* B_re      = (const float*)d_in[3];
  const float* B_im      = (const float*)d_in[4];
  const float* C_re      = (const float*)d_in[5];
  const float* C_im      = (const float*)d_in[6];
  const float* Dv        = (const float*)d_in[7];
  const float* gamma_log = (const float*)d_in[8];

  char* ws = (char*)d_ws;
  u16*    x_bf  = (u16*)ws;                                  // 16 MB
  u16*    s_bf  = (u16*)(ws + ((size_t)16 << 20));           // 32 MB
  float*  Bu    = (float*)(ws + ((size_t)48 << 20));         // 64 MB
  u16*    Bcat  = (u16*)(ws + ((size_t)112 << 20));          // 256 KB
  u16*    Ccat  = (u16*)(ws + ((size_t)112 << 20) + 262144); // 256 KB
  float2* lam   = (float2*)(ws + ((size_t)112 << 20) + 524288);
  float2* lam64 = (float2*)(ws + ((size_t)112 << 20) + 524288 + 4096);
  float2* carry = (float2*)(ws + ((size_t)113 << 20));       // 1 MB
  float2* corr  = (float2*)(ws + ((size_t)114 << 20));       // 1 MB

  prep_kernel<<<2817, 256, 0, stream>>>(x, nu_log, theta_log, B_re, B_im,
                                        C_re, C_im, gamma_log,
                                        x_bf, Bcat, Ccat, lam, lam64);

  gemm_bt_kernel<false><<<dim3(NCAT / 128, L_SEQ / 128), 256, 0, stream>>>(
      x_bf, Bcat, Bu, L_SEQ, NCAT, HDIM, nullptr, nullptr);

  scan_carry_kernel<<<NCHUNK, 256, 0, stream>>>((const float2*)Bu, lam, carry);
  carry_scan_kernel<<<1, 256, 0, stream>>>(carry, lam64, corr);
  scan_apply_kernel<<<NCHUNK, 256, 0, stream>>>((const float2*)Bu, lam, corr, s_bf);

  gemm_bt_kernel<true><<<dim3(HDIM / 128, L_SEQ / 128), 256, 0, stream>>>(
      s_bf, Ccat, (float*)d_out, L_SEQ, HDIM, NCAT, x, Dv);
}

// Round 2
// 94.311 us; speedup vs baseline: 1.7144x; 1.7144x over previous
//
#include <hip/hip_runtime.h>

#define L_SEQ 32768
#define NDIM 256
#define HDIM 256
#define NCAT 512   // 2*NDIM (re/im interleaved)
#define LC 64      // scan chunk length
#define NCHUNK 512 // L_SEQ / LC

typedef unsigned short u16;
typedef unsigned int u32;
typedef __bf16 bf16x8 __attribute__((ext_vector_type(8)));
typedef float f32x4 __attribute__((ext_vector_type(4)));
typedef __attribute__((address_space(3))) void lds_void;
typedef const __attribute__((address_space(1))) void gbl_void;

__device__ __forceinline__ u16 f2bf(float f) {
  u32 u = __builtin_bit_cast(u32, f);
  u = u + 0x7fffu + ((u >> 16) & 1u);
  return (u16)(u >> 16);
}

// ---------------------------------------------------------------------------
// PREP: x -> bf16, build Bcat (512x256 bf16), Ccat (256x512 bf16), lambda tables
// ---------------------------------------------------------------------------
__global__ __launch_bounds__(256) void prep_kernel(
    const float* __restrict__ x,
    const float* __restrict__ nu_log, const float* __restrict__ theta_log,
    const float* __restrict__ B_re, const float* __restrict__ B_im,
    const float* __restrict__ C_re, const float* __restrict__ C_im,
    const float* __restrict__ gamma_log,
    u16* __restrict__ x_bf, u16* __restrict__ Bcat, u16* __restrict__ Ccat,
    float2* __restrict__ lam, float2* __restrict__ lam64)
{
  const int blk = blockIdx.x, tid = threadIdx.x;
  if (blk < 2048) {
    // x: 8,388,608 floats = 2048 blocks * 1024 float4
    const float4* src = ((const float4*)x) + (size_t)blk * 1024;
    ushort4* dst = ((ushort4*)x_bf) + (size_t)blk * 1024;
#pragma unroll
    for (int j = 0; j < 4; ++j) {
      float4 v = src[j * 256 + tid];
      dst[j * 256 + tid] = make_ushort4(f2bf(v.x), f2bf(v.y), f2bf(v.z), f2bf(v.w));
    }
  } else if (blk < 2560) {
    // Bcat row b2: even row = B_re * e^gamma, odd row = B_im * e^gamma
    int b2 = blk - 2048;
    int jj = b2 >> 1, p = b2 & 1;
    float g = expf(gamma_log[jj]);
    const float* src = (p ? B_im : B_re) + (size_t)jj * HDIM;
    Bcat[(size_t)b2 * HDIM + tid] = f2bf(src[tid] * g);
  } else if (blk < 2816) {
    // Ccat row h: col 2j = C_re[h][j], col 2j+1 = -C_im[h][j]
    int h = blk - 2560;
#pragma unroll
    for (int half = 0; half < 2; ++half) {
      int nc = half * 256 + tid;
      int jj = nc >> 1, p = nc & 1;
      float v = p ? -C_im[(size_t)h * NDIM + jj] : C_re[(size_t)h * NDIM + jj];
      Ccat[(size_t)h * NCAT + nc] = f2bf(v);
    }
  } else {
    // lambda and lambda^LC tables
    float nu_e = expf(nu_log[tid]);
    float th = expf(theta_log[tid]);
    float r = expf(-nu_e);
    lam[tid] = make_float2(r * cosf(th), r * sinf(th));
    float r64 = expf(-(float)LC * nu_e);
    float ph = (float)LC * th;
    lam64[tid] = make_float2(r64 * cosf(ph), r64 * sinf(ph));
  }
}

// ---------------------------------------------------------------------------
// GEMM (B^T layout): C[m][n] = sum_k A[m][k] * Bm[n][k]; optional +x*D epilogue
// 128x128 tile, BK=32, 4 waves, m97-style global_load_lds staging
// ---------------------------------------------------------------------------
template <bool EPI_XD>
__global__ __launch_bounds__(256) void gemm_bt_kernel(
    const u16* __restrict__ A,   // M x K bf16
    const u16* __restrict__ Bm,  // N x K bf16
    float* __restrict__ Cout,    // M x N f32
    int M, int N, int K,
    const float* __restrict__ xin, const float* __restrict__ Dv)
{
  constexpr int BM = 128, BN = 128, BK = 32;
  __shared__ u16 lA[BM * BK];
  __shared__ u16 lB[BN * BK];
  const int tid = threadIdx.x;
  const int lane = tid & 63, wave = tid >> 6;
  const int bn = blockIdx.x, bm = blockIdx.y;
  const int row0 = bm * BM, col0 = bn * BN;
  const int wm = (wave >> 1) * 64, wn = (wave & 1) * 64;
  const int fr = lane & 15, fo = (lane >> 4) * 8;

  f32x4 acc[4][4] = {};
  const int nkt = K / BK;
  for (int kt = 0; kt < nkt; ++kt) {
    const int k0 = kt * BK;
#pragma unroll
    for (int j = 0; j < 2; ++j) {
      int chunk = j * 256 + tid;          // 512 chunks of 16B per tile
      int r = chunk >> 2, c = chunk & 3;
      const u16* ga = A + (size_t)(row0 + r) * K + (k0 + c * 8);
      const u16* gb = Bm + (size_t)(col0 + r) * K + (k0 + c * 8);
      __builtin_amdgcn_global_load_lds((gbl_void*)ga, (lds_void*)&lA[chunk * 8], 16, 0, 0);
      __builtin_amdgcn_global_load_lds((gbl_void*)gb, (lds_void*)&lB[chunk * 8], 16, 0, 0);
    }
    __syncthreads();

    bf16x8 af[4], bfr[4];
#pragma unroll
    for (int i = 0; i < 4; ++i) {
      af[i]  = *reinterpret_cast<const bf16x8*>(&lA[(wm + i * 16 + fr) * BK + fo]);
      bfr[i] = *reinterpret_cast<const bf16x8*>(&lB[(wn + i * 16 + fr) * BK + fo]);
    }
#pragma unroll
    for (int i = 0; i < 4; ++i)
#pragma unroll
      for (int j = 0; j < 4; ++j)
        acc[i][j] = __builtin_amdgcn_mfma_f32_16x16x32_bf16(af[i], bfr[j], acc[i][j], 0, 0, 0);
    __syncthreads();
  }

  // C/D layout: col = lane&15, row = (lane>>4)*4 + reg
  const int fq = lane >> 4;
#pragma unroll
  for (int i = 0; i < 4; ++i)
#pragma unroll
    for (int j = 0; j < 4; ++j) {
      int cg = col0 + wn + j * 16 + fr;
#pragma unroll
      for (int r = 0; r < 4; ++r) {
        int rg = row0 + wm + i * 16 + fq * 4 + r;
        float v = acc[i][j][r];
        if (EPI_XD) v += xin[(size_t)rg * N + cg] * Dv[cg];
        Cout[(size_t)rg * N + cg] = v;
      }
    }
}

// ---------------------------------------------------------------------------
// Scan phase 1: per-chunk final state (read-only over Bu)
// ---------------------------------------------------------------------------
__global__ __launch_bounds__(256) void scan_carry_kernel(
    const float2* __restrict__ Bu2, const float2* __restrict__ lam,
    float2* __restrict__ carry)
{
  const int n = threadIdx.x, b = blockIdx.x;
  const float2 la = lam[n];
  float sre = 0.f, sim = 0.f;
  const float2* p = Bu2 + (size_t)b * LC * NDIM + n;
#pragma unroll 8
  for (int j = 0; j < LC; ++j) {
    float2 bu = p[(size_t)j * NDIM];
    float nre = la.x * sre - la.y * sim + bu.x;
    float nim = la.x * sim + la.y * sre + bu.y;
    sre = nre; sim = nim;
  }
  carry[(size_t)b * NDIM + n] = make_float2(sre, sim);
}

// ---------------------------------------------------------------------------
// Scan phase 2: cross-chunk scan, log-depth Hillis-Steele in LDS.
// One block per channel n; thread b holds chunk b's carry.
// corr[b] = state entering chunk b (corr[0] = 0)
// ---------------------------------------------------------------------------
__global__ __launch_bounds__(512) void carry_scan_kernel(
    const float2* __restrict__ carry, const float2* __restrict__ lam64,
    float2* __restrict__ corr)
{
  __shared__ float4 e[NCHUNK];   // (a.re, a.im, v.re, v.im)
  const int n = blockIdx.x;      // channel
  const int b = threadIdx.x;     // chunk
  float2 a = lam64[n];
  float2 v = carry[(size_t)b * NDIM + n];
  e[b] = make_float4(a.x, a.y, v.x, v.y);
  __syncthreads();
#pragma unroll
  for (int d = 1; d < NCHUNK; d <<= 1) {
    float4 prev;
    if (b >= d) prev = e[b - d];
    __syncthreads();
    if (b >= d) {
      float2 ap = make_float2(prev.x, prev.y), vp = make_float2(prev.z, prev.w);
      float2 na, nv;
      na.x = a.x * ap.x - a.y * ap.y;
      na.y = a.x * ap.y + a.y * ap.x;
      nv.x = a.x * vp.x - a.y * vp.y + v.x;
      nv.y = a.x * vp.y + a.y * vp.x + v.y;
      a = na; v = nv;
      e[b] = make_float4(a.x, a.y, v.x, v.y);
    }
    __syncthreads();
  }
  if (b == 0) corr[n] = make_float2(0.f, 0.f);
  if (b < NCHUNK - 1) corr[(size_t)(b + 1) * NDIM + n] = v;
}

// ---------------------------------------------------------------------------
// Scan phase 3: recompute chunk seeded with carry, emit bf16 states (L x 512)
// ---------------------------------------------------------------------------
__global__ __launch_bounds__(256) void scan_apply_kernel(
    const float2* __restrict__ Bu2, const float2* __restrict__ lam,
    const float2* __restrict__ corr, u16* __restrict__ Sbf)
{
  const int n = threadIdx.x, b = blockIdx.x;
  const float2 la = lam[n];
  const float2 c = corr[(size_t)b * NDIM + n];
  float sre = c.x, sim = c.y;
  const float2* p = Bu2 + (size_t)b * LC * NDIM + n;
  ushort2* q = ((ushort2*)Sbf) + (size_t)b * LC * NDIM + n;
#pragma unroll 4
  for (int j = 0; j < LC; ++j) {
    float2 bu = p[(size_t)j * NDIM];
    float nre = la.x * sre - la.y * sim + bu.x;
    float nim = la.x * sim + la.y * sre + bu.y;
    sre = nre; sim = nim;
    q[(size_t)j * NDIM] = make_ushort2(f2bf(sre), f2bf(sim));
  }
}

// ---------------------------------------------------------------------------
extern "C" void kernel_launch(void* const* d_in, const int* in_sizes, int n_in,
                              void* d_out, int out_size, void* d_ws, size_t ws_size,
                              hipStream_t stream)
{
  (void)in_sizes; (void)n_in; (void)out_size; (void)ws_size;
  const float* x         = (const float*)d_in[0];
  const float* nu_log    = (const float*)d_in[1];
  const float* theta_log = (const float*)d_in[2];
  const float* B_re      = (const float*)d_in[3];
  const float* B_im      = (const float*)d_in[4];
  const float* C_re      = (const float*)d_in[5];
  const float* C_im      = (const float*)d_in[6];
  const float* Dv        = (const float*)d_in[7];
  const float* gamma_log = (const float*)d_in[8];

  char* ws = (char*)d_ws;
  u16*    x_bf  = (u16*)ws;                                  // 16 MB
  u16*    s_bf  = (u16*)(ws + ((size_t)16 << 20));           // 32 MB
  float*  Bu    = (float*)(ws + ((size_t)48 << 20));         // 64 MB
  u16*    Bcat  = (u16*)(ws + ((size_t)112 << 20));          // 256 KB
  u16*    Ccat  = (u16*)(ws + ((size_t)112 << 20) + 262144); // 256 KB
  float2* lam   = (float2*)(ws + ((size_t)112 << 20) + 524288);
  float2* lam64 = (float2*)(ws + ((size_t)112 << 20) + 524288 + 4096);
  float2* carry = (float2*)(ws + ((size_t)113 << 20));       // 1 MB
  float2* corr  = (float2*)(ws + ((size_t)114 << 20));       // 1 MB

  prep_kernel<<<2817, 256, 0, stream>>>(x, nu_log, theta_log, B_re, B_im,
                                        C_re, C_im, gamma_log,
                                        x_bf, Bcat, Ccat, lam, lam64);

  gemm_bt_kernel<false><<<dim3(NCAT / 128, L_SEQ / 128), 256, 0, stream>>>(
      x_bf, Bcat, Bu, L_SEQ, NCAT, HDIM, nullptr, nullptr);

  scan_carry_kernel<<<NCHUNK, 256, 0, stream>>>((const float2*)Bu, lam, carry);
  carry_scan_kernel<<<NDIM, 512, 0, stream>>>(carry, lam64, corr);
  scan_apply_kernel<<<NCHUNK, 256, 0, stream>>>((const float2*)Bu, lam, corr, s_bf);

  gemm_bt_kernel<true><<<dim3(HDIM / 128, L_SEQ / 128), 256, 0, stream>>>(
      s_bf, Ccat, (float*)d_out, L_SEQ, HDIM, NCAT, x, Dv);
}

// Round 3
// 82.768 us; speedup vs baseline: 1.9535x; 1.1395x over previous
//
#include <hip/hip_runtime.h>

#define L_SEQ 32768
#define NDIM 256
#define HDIM 256
#define NCAT 512   // 2*NDIM (re/im interleaved)
#define LC 64      // scan chunk length
#define NCHUNK 512 // L_SEQ / LC

typedef unsigned short u16;
typedef unsigned int u32;
typedef __bf16 bf16x8 __attribute__((ext_vector_type(8)));
typedef float f32x4 __attribute__((ext_vector_type(4)));
typedef __attribute__((address_space(3))) void lds_void;
typedef const __attribute__((address_space(1))) void gbl_void;

__device__ __forceinline__ u16 f2bf(float f) {
  u32 u = __builtin_bit_cast(u32, f);
  u = u + 0x7fffu + ((u >> 16) & 1u);
  return (u16)(u >> 16);
}
__device__ __forceinline__ float bf2f(u16 v) {
  u32 u = ((u32)v) << 16;
  return __builtin_bit_cast(float, u);
}

// ---------------------------------------------------------------------------
// PREP: x -> bf16, build Bcat (512x256 bf16), Ccat (256x512 bf16), lambda tables
// ---------------------------------------------------------------------------
__global__ __launch_bounds__(256) void prep_kernel(
    const float* __restrict__ x,
    const float* __restrict__ nu_log, const float* __restrict__ theta_log,
    const float* __restrict__ B_re, const float* __restrict__ B_im,
    const float* __restrict__ C_re, const float* __restrict__ C_im,
    const float* __restrict__ gamma_log,
    u16* __restrict__ x_bf, u16* __restrict__ Bcat, u16* __restrict__ Ccat,
    float2* __restrict__ lam, float2* __restrict__ lam64)
{
  const int blk = blockIdx.x, tid = threadIdx.x;
  if (blk < 2048) {
    // x: 8,388,608 floats = 2048 blocks * 1024 float4
    const float4* src = ((const float4*)x) + (size_t)blk * 1024;
    ushort4* dst = ((ushort4*)x_bf) + (size_t)blk * 1024;
#pragma unroll
    for (int j = 0; j < 4; ++j) {
      float4 v = src[j * 256 + tid];
      dst[j * 256 + tid] = make_ushort4(f2bf(v.x), f2bf(v.y), f2bf(v.z), f2bf(v.w));
    }
  } else if (blk < 2560) {
    // Bcat row b2: even row = B_re * e^gamma, odd row = B_im * e^gamma
    int b2 = blk - 2048;
    int jj = b2 >> 1, p = b2 & 1;
    float g = expf(gamma_log[jj]);
    const float* src = (p ? B_im : B_re) + (size_t)jj * HDIM;
    Bcat[(size_t)b2 * HDIM + tid] = f2bf(src[tid] * g);
  } else if (blk < 2816) {
    // Ccat row h: col 2j = C_re[h][j], col 2j+1 = -C_im[h][j]
    int h = blk - 2560;
#pragma unroll
    for (int half = 0; half < 2; ++half) {
      int nc = half * 256 + tid;
      int jj = nc >> 1, p = nc & 1;
      float v = p ? -C_im[(size_t)h * NDIM + jj] : C_re[(size_t)h * NDIM + jj];
      Ccat[(size_t)h * NCAT + nc] = f2bf(v);
    }
  } else {
    // lambda and lambda^LC tables
    float nu_e = expf(nu_log[tid]);
    float th = expf(theta_log[tid]);
    float r = expf(-nu_e);
    lam[tid] = make_float2(r * cosf(th), r * sinf(th));
    float r64 = expf(-(float)LC * nu_e);
    float ph = (float)LC * th;
    lam64[tid] = make_float2(r64 * cosf(ph), r64 * sinf(ph));
  }
}

// ---------------------------------------------------------------------------
// GEMM (B^T layout): C[m][n] = sum_k A[m][k] * Bm[n][k]
// 128x128 tile, BK=32, 4 waves, m97-style global_load_lds staging.
// OUT_BF16: write bf16 (for Bu). EPI_XD: += bf16(x)*D epilogue (for y).
// ---------------------------------------------------------------------------
template <bool EPI_XD, bool OUT_BF16>
__global__ __launch_bounds__(256) void gemm_bt_kernel(
    const u16* __restrict__ A,   // M x K bf16
    const u16* __restrict__ Bm,  // N x K bf16
    void* __restrict__ Cout,     // M x N (f32 or bf16)
    int M, int N, int K,
    const u16* __restrict__ xbf, const float* __restrict__ Dv)
{
  constexpr int BM = 128, BN = 128, BK = 32;
  __shared__ u16 lA[BM * BK];
  __shared__ u16 lB[BN * BK];
  const int tid = threadIdx.x;
  const int lane = tid & 63, wave = tid >> 6;
  const int bn = blockIdx.x, bm = blockIdx.y;
  const int row0 = bm * BM, col0 = bn * BN;
  const int wm = (wave >> 1) * 64, wn = (wave & 1) * 64;
  const int fr = lane & 15, fo = (lane >> 4) * 8;

  f32x4 acc[4][4] = {};
  const int nkt = K / BK;
  for (int kt = 0; kt < nkt; ++kt) {
    const int k0 = kt * BK;
#pragma unroll
    for (int j = 0; j < 2; ++j) {
      int chunk = j * 256 + tid;          // 512 chunks of 16B per tile
      int r = chunk >> 2, c = chunk & 3;
      const u16* ga = A + (size_t)(row0 + r) * K + (k0 + c * 8);
      const u16* gb = Bm + (size_t)(col0 + r) * K + (k0 + c * 8);
      __builtin_amdgcn_global_load_lds((gbl_void*)ga, (lds_void*)&lA[chunk * 8], 16, 0, 0);
      __builtin_amdgcn_global_load_lds((gbl_void*)gb, (lds_void*)&lB[chunk * 8], 16, 0, 0);
    }
    __syncthreads();

    bf16x8 af[4], bfr[4];
#pragma unroll
    for (int i = 0; i < 4; ++i) {
      af[i]  = *reinterpret_cast<const bf16x8*>(&lA[(wm + i * 16 + fr) * BK + fo]);
      bfr[i] = *reinterpret_cast<const bf16x8*>(&lB[(wn + i * 16 + fr) * BK + fo]);
    }
#pragma unroll
    for (int i = 0; i < 4; ++i)
#pragma unroll
      for (int j = 0; j < 4; ++j)
        acc[i][j] = __builtin_amdgcn_mfma_f32_16x16x32_bf16(af[i], bfr[j], acc[i][j], 0, 0, 0);
    __syncthreads();
  }

  // C/D layout: col = lane&15, row = (lane>>4)*4 + reg
  const int fq = lane >> 4;
#pragma unroll
  for (int i = 0; i < 4; ++i)
#pragma unroll
    for (int j = 0; j < 4; ++j) {
      int cg = col0 + wn + j * 16 + fr;
      float dvc = EPI_XD ? Dv[cg] : 0.f;
#pragma unroll
      for (int r = 0; r < 4; ++r) {
        int rg = row0 + wm + i * 16 + fq * 4 + r;
        float v = acc[i][j][r];
        if (EPI_XD) v += bf2f(xbf[(size_t)rg * N + cg]) * dvc;
        if (OUT_BF16) ((u16*)Cout)[(size_t)rg * N + cg] = f2bf(v);
        else          ((float*)Cout)[(size_t)rg * N + cg] = v;
      }
    }
}

// ---------------------------------------------------------------------------
// Scan phase 1: per-chunk final state (read-only over bf16 Bu)
// ---------------------------------------------------------------------------
__global__ __launch_bounds__(256) void scan_carry_kernel(
    const ushort2* __restrict__ Bu2, const float2* __restrict__ lam,
    float2* __restrict__ carry)
{
  const int n = threadIdx.x, b = blockIdx.x;
  const float2 la = lam[n];
  float sre = 0.f, sim = 0.f;
  const ushort2* p = Bu2 + (size_t)b * LC * NDIM + n;
#pragma unroll 8
  for (int j = 0; j < LC; ++j) {
    ushort2 bu = p[(size_t)j * NDIM];
    float bre = bf2f(bu.x), bim = bf2f(bu.y);
    float nre = la.x * sre - la.y * sim + bre;
    float nim = la.x * sim + la.y * sre + bim;
    sre = nre; sim = nim;
  }
  carry[(size_t)b * NDIM + n] = make_float2(sre, sim);
}

// ---------------------------------------------------------------------------
// Scan phase 2: cross-chunk scan, log-depth Hillis-Steele in LDS.
// One block per channel n; thread b holds chunk b's carry.
// corr[b] = state entering chunk b (corr[0] = 0)
// ---------------------------------------------------------------------------
__global__ __launch_bounds__(512) void carry_scan_kernel(
    const float2* __restrict__ carry, const float2* __restrict__ lam64,
    float2* __restrict__ corr)
{
  __shared__ float4 e[NCHUNK];   // (a.re, a.im, v.re, v.im)
  const int n = blockIdx.x;      // channel
  const int b = threadIdx.x;     // chunk
  float2 a = lam64[n];
  float2 v = carry[(size_t)b * NDIM + n];
  e[b] = make_float4(a.x, a.y, v.x, v.y);
  __syncthreads();
#pragma unroll
  for (int d = 1; d < NCHUNK; d <<= 1) {
    float4 prev;
    if (b >= d) prev = e[b - d];
    __syncthreads();
    if (b >= d) {
      float2 ap = make_float2(prev.x, prev.y), vp = make_float2(prev.z, prev.w);
      float2 na, nv;
      na.x = a.x * ap.x - a.y * ap.y;
      na.y = a.x * ap.y + a.y * ap.x;
      nv.x = a.x * vp.x - a.y * vp.y + v.x;
      nv.y = a.x * vp.y + a.y * vp.x + v.y;
      a = na; v = nv;
      e[b] = make_float4(a.x, a.y, v.x, v.y);
    }
    __syncthreads();
  }
  if (b == 0) corr[n] = make_float2(0.f, 0.f);
  if (b < NCHUNK - 1) corr[(size_t)(b + 1) * NDIM + n] = v;
}

// ---------------------------------------------------------------------------
// Scan phase 3: recompute chunk seeded with carry, emit bf16 states (L x 512)
// ---------------------------------------------------------------------------
__global__ __launch_bounds__(256) void scan_apply_kernel(
    const ushort2* __restrict__ Bu2, const float2* __restrict__ lam,
    const float2* __restrict__ corr, u16* __restrict__ Sbf)
{
  const int n = threadIdx.x, b = blockIdx.x;
  const float2 la = lam[n];
  const float2 c = corr[(size_t)b * NDIM + n];
  float sre = c.x, sim = c.y;
  const ushort2* p = Bu2 + (size_t)b * LC * NDIM + n;
  ushort2* q = ((ushort2*)Sbf) + (size_t)b * LC * NDIM + n;
#pragma unroll 4
  for (int j = 0; j < LC; ++j) {
    ushort2 bu = p[(size_t)j * NDIM];
    float bre = bf2f(bu.x), bim = bf2f(bu.y);
    float nre = la.x * sre - la.y * sim + bre;
    float nim = la.x * sim + la.y * sre + bim;
    sre = nre; sim = nim;
    q[(size_t)j * NDIM] = make_ushort2(f2bf(sre), f2bf(sim));
  }
}

// ---------------------------------------------------------------------------
extern "C" void kernel_launch(void* const* d_in, const int* in_sizes, int n_in,
                              void* d_out, int out_size, void* d_ws, size_t ws_size,
                              hipStream_t stream)
{
  (void)in_sizes; (void)n_in; (void)out_size; (void)ws_size;
  const float* x         = (const float*)d_in[0];
  const float* nu_log    = (const float*)d_in[1];
  const float* theta_log = (const float*)d_in[2];
  const float* B_re      = (const float*)d_in[3];
  const float* B_im      = (const float*)d_in[4];
  const float* C_re      = (const float*)d_in[5];
  const float* C_im      = (const float*)d_in[6];
  const float* Dv        = (const float*)d_in[7];
  const float* gamma_log = (const float*)d_in[8];

  char* ws = (char*)d_ws;
  u16*    x_bf  = (u16*)ws;                                  // 16 MB
  u16*    s_bf  = (u16*)(ws + ((size_t)16 << 20));           // 32 MB
  u16*    Bu_bf = (u16*)(ws + ((size_t)48 << 20));           // 32 MB (bf16 interleaved re/im)
  u16*    Bcat  = (u16*)(ws + ((size_t)80 << 20));           // 256 KB
  u16*    Ccat  = (u16*)(ws + ((size_t)80 << 20) + 262144);  // 256 KB
  float2* lam   = (float2*)(ws + ((size_t)80 << 20) + 524288);
  float2* lam64 = (float2*)(ws + ((size_t)80 << 20) + 524288 + 4096);
  float2* carry = (float2*)(ws + ((size_t)81 << 20));        // 1 MB
  float2* corr  = (float2*)(ws + ((size_t)82 << 20));        // 1 MB

  prep_kernel<<<2817, 256, 0, stream>>>(x, nu_log, theta_log, B_re, B_im,
                                        C_re, C_im, gamma_log,
                                        x_bf, Bcat, Ccat, lam, lam64);

  gemm_bt_kernel<false, true><<<dim3(NCAT / 128, L_SEQ / 128), 256, 0, stream>>>(
      x_bf, Bcat, Bu_bf, L_SEQ, NCAT, HDIM, nullptr, nullptr);

  scan_carry_kernel<<<NCHUNK, 256, 0, stream>>>((const ushort2*)Bu_bf, lam, carry);
  carry_scan_kernel<<<NDIM, 512, 0, stream>>>(carry, lam64, corr);
  scan_apply_kernel<<<NCHUNK, 256, 0, stream>>>((const ushort2*)Bu_bf, lam, corr, s_bf);

  gemm_bt_kernel<true, false><<<dim3(HDIM / 128, L_SEQ / 128), 256, 0, stream>>>(
      s_bf, Ccat, (float*)d_out, L_SEQ, HDIM, NCAT, x_bf, Dv);
}